// Round 14
// baseline (46.758 us; speedup 1.0000x reference)
//
#include <hip/hip_runtime.h>
#include <hip/hip_bf16.h>

// out[b][o] = sum_{ij,kl} w01[b,ij] * w23[b,kl] * T2[ij][kl*32+o]
//   w01 = a0 (x) a1  (bf16, precomputed),  w23 = a2 (x) a3 (fp32)
// Stage 1 = GEMM M=32(b) x N=34848(kl,o) x K=1089(ij) via mfma_32x32x16_bf16;
// each one-wave block owns one kl (32 columns) and one ij-half (K=560).
// Epilogue scales by w23[b][kl] and atomics into r12's NT=64 shared tiles.
#define HSZ 32
#define NIJ 1089            // 33^2 real ij rows
#define NIJP 1120           // padded to 70*16 (two 560 halves)
#define HALFK 560           // K per block = 35 steps of 16
#define NCOL 34848          // 33^2 * 32 columns of T2
#define NBLK 2178           // 1089 kl-chunks * 2 ij-halves
#define NT 64               // shared partial tiles (contention 2178/64 ~ 34)

// ws (bytes): w01b @ 0 (32*1120*2 = 71,680); w23f @ 131072 (32*1089*4);
//             tiles @ 524288 (64*1024*4 = 262,144)
#define OFF_W23   131072
#define OFF_TILES 524288

typedef short bf16x8 __attribute__((ext_vector_type(8)));
typedef float f32x16 __attribute__((ext_vector_type(16)));

__device__ inline short f2bf(float f) {
  __hip_bfloat16 h = __float2bfloat16(f);  // RTNE; pairs into v_cvt_pk_bf16_f32
  return __builtin_bit_cast(short, h);
}

// k_pre: 96 blocks. 0..31: w01b[b][*] (bf16, zero-padded) + w23f[b][*].
//        32..95: zero the NT tiles (64 blocks * 4 KB).
__global__ __launch_bounds__(256) void k_pre(const float* __restrict__ nh,
                                             short* __restrict__ w01b,
                                             float* __restrict__ w23f,
                                             float* __restrict__ tiles) {
  const int blk = (int)blockIdx.x;
  const int t = (int)threadIdx.x;
  if (blk < 32) {
    const int b = blk;
    const float* row = nh + b * 128;
    for (int ij = t; ij < NIJP; ij += 256) {
      float v = 0.f;
      if (ij < NIJ) {
        const int i = ij / 33;
        const int j = ij - i * 33;
        const float a0 = (i < HSZ) ? row[i] : 1.0f;
        const float a1 = (j < HSZ) ? row[32 + j] : 1.0f;
        v = a0 * a1;
      }
      w01b[b * NIJP + ij] = f2bf(v);
    }
    for (int kl = t; kl < NIJ; kl += 256) {
      const int k = kl / 33;
      const int l = kl - k * 33;
      const float a2 = (k < HSZ) ? row[64 + k] : 1.0f;
      const float a3 = (l < HSZ) ? row[96 + l] : 1.0f;
      w23f[b * NIJ + kl] = a2 * a3;
    }
  } else {
    ((float4*)tiles)[(blk - 32) * 256 + t] = make_float4(0.f, 0.f, 0.f, 0.f);
  }
}

// Stage 1: one wave per block. beta -> (c = kl chunk, half = ij half).
// lane l: bo = l&31 (A row=b / B col=o), g = l>>5 (k-group).
__global__ __launch_bounds__(64) void k_main(const float* __restrict__ T,
                                             const short* __restrict__ w01b,
                                             const float* __restrict__ w23f,
                                             float* __restrict__ tiles) {
  const int beta = (int)blockIdx.x;
  const int c = beta >> 1;
  const int half = beta & 1;
  const int ij0 = half * HALFK;
  const int l = (int)threadIdx.x;
  const int bo = l & 31;
  const int g = l >> 5;
  const int n0 = c * 32 + bo;

  // Load one K-step: 8 T dwords (row-clamped; w01b pad rows are 0) + 16B w01b.
#define LOADF(tbuf, wreg, it)                                  \
  {                                                            \
    const int base = ij0 + (it) * 16 + 8 * g;                  \
    _Pragma("unroll")                                          \
    for (int e = 0; e < 8; ++e) {                              \
      int rr = base + e;                                       \
      rr = (rr < NIJ) ? rr : (NIJ - 1);                        \
      tbuf[e] = T[(size_t)rr * NCOL + n0];                     \
    }                                                          \
    wreg = *(const bf16x8*)(w01b + (size_t)bo * NIJP + base);  \
  }

  f32x16 acc = {};
  float tv[8];
  bf16x8 wv;
  LOADF(tv, wv, 0);

  // r12's dist-1 rolling-prefetch idiom, A-side now a pure vector load.
  for (int it = 0; it < 35; ++it) {
    float tn[8];
    bf16x8 wn;
    if (it < 34) LOADF(tn, wn, it + 1);
    bf16x8 bfr;
#pragma unroll
    for (int e = 0; e < 8; ++e) bfr[e] = f2bf(tv[e]);
    acc = __builtin_amdgcn_mfma_f32_32x32x16_bf16(wv, bfr, acc, 0, 0, 0);
#pragma unroll
    for (int e = 0; e < 8; ++e) tv[e] = tn[e];
    wv = wn;
  }
#undef LOADF

  // Scale by w23[b][c] and accumulate into shared tiles (r12 epilogue).
  // C/D layout (m74/m101): col=lane&31, row=(r&3)+8*(r>>2)+4*(lane>>5)
  float* tp = tiles + (size_t)(beta & (NT - 1)) * 1024;
#pragma unroll
  for (int r = 0; r < 16; ++r) {
    const int brow = (r & 3) + 8 * (r >> 2) + 4 * g;
    const float w = w23f[brow * NIJ + c];  // broadcast, L2-hot
    atomicAdd(tp + brow * 32 + bo, acc[r] * w);
  }
}

// Final reduce (r12 verbatim): out[idx] = sum over NT tiles.
__global__ __launch_bounds__(256) void k_red(const float* __restrict__ tiles,
                                             float* __restrict__ out) {
  const int idx = blockIdx.x * 256 + (int)threadIdx.x;
  float s = 0.f;
  for (int t = 0; t < NT; ++t) s += tiles[(size_t)t * 1024 + idx];
  out[idx] = s;
}

extern "C" void kernel_launch(void* const* d_in, const int* in_sizes, int n_in,
                              void* d_out, int out_size, void* d_ws, size_t ws_size,
                              hipStream_t stream) {
  const float* nh = (const float*)d_in[0];  // [32,4,32]
  const float* T  = (const float*)d_in[1];  // [33,33,33,33,32] == T2[1089][34848]
  float* out = (float*)d_out;               // [32,32] fp32
  char* ws = (char*)d_ws;
  short* w01b  = (short*)ws;
  float* w23f  = (float*)(ws + OFF_W23);
  float* tiles = (float*)(ws + OFF_TILES);

  k_pre<<<96, 256, 0, stream>>>(nh, w01b, w23f, tiles);
  k_main<<<NBLK, 64, 0, stream>>>(T, w01b, w23f, tiles);
  k_red<<<4, 256, 0, stream>>>(tiles, out);
}

// Round 15
// 44.717 us; speedup vs baseline: 1.0456x; 1.0456x over previous
//
#include <hip/hip_runtime.h>
#include <hip/hip_bf16.h>

// Problem constants
#define HSZ 32
#define HP1 33
#define M3 35937            // 33^3 (flattened j,k,l)
#define TI_STRIDE 1149984   // 33^3 * 32 floats (stride of T over i)
#define NBLK 2247           // one wave per block
#define NT 64               // partial output tiles (contention 2247/64 ~ 35)

// ws layout (bytes):
//   nhT   @ 0     : 4*33*32 floats = 16,896 B  (nhT[d][x][b]; row x=32 == 1.0)
//   tiles @ 32768 : 64*1024 floats = 262,144 B
#define OFF_TILES 32768
#define NHT_D 1056          // 33*32 floats per d-plane

typedef short bf16x8 __attribute__((ext_vector_type(8)));
typedef float f32x16 __attribute__((ext_vector_type(16)));

__device__ inline short f2bf(float f) {
  __hip_bfloat16 h = __float2bfloat16(f);  // RTNE; pairs into v_cvt_pk_bf16_f32
  return __builtin_bit_cast(short, h);
}

// Micro-prologue: 64 blocks zero the tiles; block 64 builds the transposed
// (and bias-augmented) nh table nhT[d][x][b].
__global__ __launch_bounds__(256) void k_pre(const float* __restrict__ nh,
                                             float* __restrict__ nhT,
                                             float* __restrict__ tiles) {
  const int blk = (int)blockIdx.x;
  const int t = (int)threadIdx.x;
  if (blk < 64) {
    ((float4*)tiles)[blk * 256 + t] = make_float4(0.f, 0.f, 0.f, 0.f);
  } else {
    for (int x = t; x < 4 * NHT_D; x += 256) {
      const int d = x / NHT_D;
      const int rem = x - d * NHT_D;
      const int row = rem >> 5;
      const int b = rem & 31;
      nhT[x] = (row < HSZ) ? nh[b * 128 + d * 32 + row] : 1.0f;
    }
  }
}

// Main: one wave per block; block owns m-chunk [m0, m0+16).
// acc[32b x 32o] += sum_i sum_{mm} (a0[b,i]*D[b,mm]) * T[i][mm][o] via
// v_mfma_f32_32x32x16_bf16. T read exactly once, coalesced.
// vs r12: df[8] computed in-wave from nhT (coalesced, L2-hot) -- D eliminated.
__global__ __launch_bounds__(64) void k_main(const float* __restrict__ T,
                                             const float* __restrict__ nhT,
                                             float* __restrict__ tiles) {
  const int blk = blockIdx.x;
  const int m0 = blk * 16;
  const int l = (int)threadIdx.x;  // 0..63
  const int bo = l & 31;           // A row (b) / B col (o)
  const int g = l >> 5;            // k-group: k = 8*g + e

  // Per-lane T element offsets (clamped in the tail; df=0 there)
  size_t toff[8];
#pragma unroll
  for (int e = 0; e < 8; ++e) {
    int mm = m0 + 8 * g + e;
    if (mm > M3 - 1) mm = M3 - 1;
    toff[e] = (size_t)mm * 32 + bo;
  }

  // Issue the first T row NOW; df build flies underneath it.
  float tv[8];
#pragma unroll
  for (int e = 0; e < 8; ++e) tv[e] = T[toff[e]];

  // A-side fragment df[e] = a1[j]*a2[k]*a3[l] from the transposed table:
  // all three reads are 32-lane-consecutive (coalesced), bias row baked in.
  float df[8];
#pragma unroll
  for (int e = 0; e < 8; ++e) {
    const int mm = m0 + 8 * g + e;
    const bool valid = mm < M3;
    const int mc = valid ? mm : (M3 - 1);
    const int j = mc / 1089;
    const int r = mc - j * 1089;
    const int kk = r / 33;
    const int ll = r - kk * 33;
    const float a1 = nhT[NHT_D + j * 32 + bo];        // d=1
    const float a2 = nhT[2 * NHT_D + kk * 32 + bo];   // d=2
    const float a3 = nhT[3 * NHT_D + ll * 32 + bo];   // d=3
    df[e] = valid ? (a1 * a2 * a3) : 0.0f;
  }

  f32x16 acc = {};
  float a0c = nhT[bo];  // a0 row 0 (d=0 plane)

  // r12's dist-1 rolling-prefetch loop, verbatim (a0T -> nhT plane 0).
  for (int i = 0; i < HP1; ++i) {
    float tn[8];
    float a0n = 0.f;
    if (i < HP1 - 1) {
      const float* Tn = T + (size_t)(i + 1) * TI_STRIDE;
#pragma unroll
      for (int e = 0; e < 8; ++e) tn[e] = Tn[toff[e]];
      a0n = nhT[(i + 1) * 32 + bo];
    }
    bf16x8 af, bfr;
#pragma unroll
    for (int e = 0; e < 8; ++e) {
      af[e]  = f2bf(a0c * df[e]);
      bfr[e] = f2bf(tv[e]);
    }
    acc = __builtin_amdgcn_mfma_f32_32x32x16_bf16(af, bfr, acc, 0, 0, 0);
#pragma unroll
    for (int e = 0; e < 8; ++e) tv[e] = tn[e];
    a0c = a0n;
  }

  // Accumulate into one of NT partial tiles (r12 epilogue verbatim).
  // C/D layout (m74/m101): col=lane&31, row=(r&3)+8*(r>>2)+4*(lane>>5)
  float* tp = tiles + (size_t)(blk & (NT - 1)) * 1024;
#pragma unroll
  for (int r = 0; r < 16; ++r) {
    const int brow = (r & 3) + 8 * (r >> 2) + 4 * g;
    atomicAdd(tp + brow * 32 + bo, acc[r]);
  }
}

// Final reduce (r12 verbatim): out[idx] = sum over NT tiles.
__global__ __launch_bounds__(256) void k_red(const float* __restrict__ tiles,
                                             float* __restrict__ out) {
  const int idx = blockIdx.x * 256 + (int)threadIdx.x;
  float s = 0.f;
  for (int t = 0; t < NT; ++t) s += tiles[(size_t)t * 1024 + idx];
  out[idx] = s;
}

extern "C" void kernel_launch(void* const* d_in, const int* in_sizes, int n_in,
                              void* d_out, int out_size, void* d_ws, size_t ws_size,
                              hipStream_t stream) {
  const float* nh = (const float*)d_in[0];  // [32,4,32]
  const float* T  = (const float*)d_in[1];  // [33,33,33,33,32]
  float* out = (float*)d_out;               // [32,32] fp32
  char* ws = (char*)d_ws;
  float* nhT   = (float*)ws;
  float* tiles = (float*)(ws + OFF_TILES);

  k_pre<<<65, 256, 0, stream>>>(nh, nhT, tiles);
  k_main<<<NBLK, 64, 0, stream>>>(T, nhT, tiles);
  k_red<<<4, 256, 0, stream>>>(tiles, out);
}

// Round 16
// 40.179 us; speedup vs baseline: 1.1638x; 1.1130x over previous
//
#include <hip/hip_runtime.h>
#include <hip/hip_bf16.h>

// Problem constants
#define HSZ 32
#define HP1 33
#define M3 35937            // 33^3 (flattened j,k,l)
#define M3P 35952           // padded to multiple of 16 (2247*16)
#define TI_STRIDE 1149984   // 33^3 * 32 floats (stride of T over i)
#define TIB ((size_t)TI_STRIDE * 4)
#define NBLK 2247           // one wave per block
#define NT 64               // partial output tiles (contention 2247/64 ~ 35)
#define DEPTH 8             // LDS ring slots (rows in flight)

// ws layout (bytes): a0T @ 0 ; D @ 8192 ; tiles @ 4610048
#define OFF_A0T   0
#define OFF_D     8192
#define OFF_TILES 4610048

typedef short bf16x8 __attribute__((ext_vector_type(8)));
typedef float f32x16 __attribute__((ext_vector_type(16)));

__device__ inline short f2bf(float f) {
  __hip_bfloat16 h = __float2bfloat16(f);  // RTNE; pairs into v_cvt_pk_bf16_f32
  return __builtin_bit_cast(short, h);
}

// Prologue (r12 verbatim): D[b][m]=a1*a2*a3 (0 in pad), a0T[i][b], zero tiles.
__global__ __launch_bounds__(256) void k_pre(const float* __restrict__ nh,
                                             float* __restrict__ a0T,
                                             float* __restrict__ D,
                                             float* __restrict__ tiles) {
  const int b = blockIdx.y;
  const int m = blockIdx.x * 256 + threadIdx.x;
  if (m < M3P) {
    float v = 0.f;
    if (m < M3) {
      const int j = m / 1089;
      const int r = m - j * 1089;
      const int k = r / 33;
      const int l = r - k * 33;
      const float a1 = (j < HSZ) ? nh[(b * 4 + 1) * HSZ + j] : 1.0f;
      const float a2 = (k < HSZ) ? nh[(b * 4 + 2) * HSZ + k] : 1.0f;
      const float a3 = (l < HSZ) ? nh[(b * 4 + 3) * HSZ + l] : 1.0f;
      v = a1 * a2 * a3;
    }
    D[(size_t)b * M3P + m] = v;
  }
  if (blockIdx.x == 0 && threadIdx.x < HP1) {
    const int i = threadIdx.x;
    a0T[i * 32 + b] = (i < HSZ) ? nh[(b * 4 + 0) * HSZ + i] : 1.0f;
  }
  if (b == 1 && blockIdx.x < 64) {
    ((float4*)tiles)[blockIdx.x * 256 + threadIdx.x] =
        make_float4(0.f, 0.f, 0.f, 0.f);
  }
}

// Main: one wave per block; T-rows stream through an 8-slot LDS ring via
// global_load_lds (16B/lane), counted vmcnt(14) steady state -- never 0
// until the drain tail. No barriers (single wave). Epilogue r12 verbatim.
__global__ __launch_bounds__(64) void k_main(const float* __restrict__ T,
                                             const float* __restrict__ a0T,
                                             const float* __restrict__ D,
                                             float* __restrict__ tiles) {
  __shared__ float lds[DEPTH * 512];  // 8 slots x 2048 B
  const int blk = blockIdx.x;
  const int m0 = blk * 16;
  const int l = (int)threadIdx.x;  // 0..63
  const int bo = l & 31;           // A row (b) / B col (o)
  const int g = l >> 5;            // k-group: k = 8*g + e

  // A-side D fragment (r12): D[bo][m0+8g+e]
  const float* dp = D + (size_t)bo * M3P + m0 + 8 * g;
  float df[8];
  *(float4*)(df)     = *(const float4*)(dp);
  *(float4*)(df + 4) = *(const float4*)(dp + 4);

  // a0 preload into registers (constant-indexed everywhere after unroll)
  float a0v[HP1];
#pragma unroll
  for (int i = 0; i < HP1; ++i) a0v[i] = a0T[i * 32 + bo];

  // Drain df/a0 loads BEFORE the DMA stream so vmcnt accounting stays pure.
  {
    float dsum = 0.f, asum = 0.f;
#pragma unroll
    for (int e = 0; e < 8; ++e) dsum += df[e];
#pragma unroll
    for (int i = 0; i < HP1; ++i) asum += a0v[i];
    asm volatile("" :: "v"(dsum), "v"(asum) : "memory");
  }

  // Per-lane DMA source byte offsets within a row (16B/lane, 2 halves).
  // Lane l, half h covers row floats [h*256 + 4l, +4) -> mm = m0+8h+(l>>3).
  // Invalid (pad) lanes clamp to row start: values unused (df=0 there).
  const int mrel = l >> 3;
  const size_t src0 = (m0 + mrel < M3) ? ((size_t)(m0 * 32 + l * 4) * 4) : 0;
  const size_t src1 =
      (m0 + 8 + mrel < M3) ? ((size_t)(m0 * 32 + 256 + l * 4) * 4) : 0;
  const char* Tb = (const char*)T;

#define ISSUE(row_, slot_)                                                   \
  {                                                                          \
    const char* s0p_ = Tb + (size_t)(row_)*TIB + src0;                       \
    const char* s1p_ = Tb + (size_t)(row_)*TIB + src1;                       \
    __builtin_amdgcn_global_load_lds(                                        \
        (const __attribute__((address_space(1))) void*)s0p_,                 \
        (__attribute__((address_space(3))) void*)(&lds[(slot_)*512]),        \
        16, 0, 0);                                                           \
    __builtin_amdgcn_global_load_lds(                                        \
        (const __attribute__((address_space(1))) void*)s1p_,                 \
        (__attribute__((address_space(3))) void*)(&lds[(slot_)*512 + 256]),  \
        16, 0, 0);                                                           \
  }

  // Prologue: fill the ring (16 DMA ops in flight)
  ISSUE(0, 0) ISSUE(1, 1) ISSUE(2, 2) ISSUE(3, 3)
  ISSUE(4, 4) ISSUE(5, 5) ISSUE(6, 6) ISSUE(7, 7)

  f32x16 acc = {};

#define STEP(i_, vm_, doIssue_)                                              \
  {                                                                          \
    asm volatile("s_waitcnt vmcnt(" #vm_ ")" ::: "memory");                  \
    __builtin_amdgcn_sched_barrier(0);                                       \
    float tvv[8];                                                            \
    _Pragma("unroll")                                                        \
    for (int e = 0; e < 8; ++e)                                              \
      tvv[e] = lds[((i_) % DEPTH) * 512 + (8 * g + e) * 32 + bo];            \
    asm volatile("s_waitcnt lgkmcnt(0)" ::: "memory");                       \
    if (doIssue_) ISSUE((i_) + DEPTH, (i_) % DEPTH)                          \
    bf16x8 af, bfr;                                                          \
    _Pragma("unroll")                                                        \
    for (int e = 0; e < 8; ++e) {                                            \
      af[e] = f2bf(a0v[i_] * df[e]);                                         \
      bfr[e] = f2bf(tvv[e]);                                                 \
    }                                                                        \
    acc = __builtin_amdgcn_mfma_f32_32x32x16_bf16(af, bfr, acc, 0, 0, 0);    \
  }

  // 33 explicit steps: steady vmcnt(14); descending drain from i=26.
  STEP(0, 14, 1)  STEP(1, 14, 1)  STEP(2, 14, 1)  STEP(3, 14, 1)
  STEP(4, 14, 1)  STEP(5, 14, 1)  STEP(6, 14, 1)  STEP(7, 14, 1)
  STEP(8, 14, 1)  STEP(9, 14, 1)  STEP(10, 14, 1) STEP(11, 14, 1)
  STEP(12, 14, 1) STEP(13, 14, 1) STEP(14, 14, 1) STEP(15, 14, 1)
  STEP(16, 14, 1) STEP(17, 14, 1) STEP(18, 14, 1) STEP(19, 14, 1)
  STEP(20, 14, 1) STEP(21, 14, 1) STEP(22, 14, 1) STEP(23, 14, 1)
  STEP(24, 14, 1) STEP(25, 14, 0) STEP(26, 12, 0) STEP(27, 10, 0)
  STEP(28, 8, 0)  STEP(29, 6, 0)  STEP(30, 4, 0)  STEP(31, 2, 0)
  STEP(32, 0, 0)
#undef STEP
#undef ISSUE

  // Accumulate into one of NT partial tiles (r12 epilogue verbatim).
  // C/D layout (m74/m101): col=lane&31, row=(r&3)+8*(r>>2)+4*(lane>>5)
  float* tp = tiles + (size_t)(blk & (NT - 1)) * 1024;
#pragma unroll
  for (int r = 0; r < 16; ++r) {
    const int brow = (r & 3) + 8 * (r >> 2) + 4 * g;
    atomicAdd(tp + brow * 32 + bo, acc[r]);
  }
}

// Final reduce (r12 verbatim): out[idx] = sum over NT tiles.
__global__ __launch_bounds__(256) void k_red(const float* __restrict__ tiles,
                                             float* __restrict__ out) {
  const int idx = blockIdx.x * 256 + (int)threadIdx.x;
  float s = 0.f;
  for (int t = 0; t < NT; ++t) s += tiles[(size_t)t * 1024 + idx];
  out[idx] = s;
}

extern "C" void kernel_launch(void* const* d_in, const int* in_sizes, int n_in,
                              void* d_out, int out_size, void* d_ws, size_t ws_size,
                              hipStream_t stream) {
  const float* nh = (const float*)d_in[0];  // [32,4,32]
  const float* T  = (const float*)d_in[1];  // [33,33,33,33,32]
  float* out = (float*)d_out;               // [32,32] fp32
  char* ws = (char*)d_ws;
  float* a0T   = (float*)(ws + OFF_A0T);
  float* D     = (float*)(ws + OFF_D);
  float* tiles = (float*)(ws + OFF_TILES);

  k_pre<<<dim3(141, 32), 256, 0, stream>>>(nh, a0T, D, tiles);
  k_main<<<NBLK, 64, 0, stream>>>(T, a0T, D, tiles);
  k_red<<<4, 256, 0, stream>>>(tiles, out);
}